// Round 12
// baseline (71.275 us; speedup 1.0000x reference)
//
#include <hip/hip_runtime.h>

// QuadraticWeightedKappa: N=4194304 rows x 5 classes (f32 logits), int32
// targets. Output: one f32 scalar -kappa.
//
// Correctness model (locked in R5, absmax=0.0): counts = first-max-wins raw
// argmax; finalize = f32 XLA-CPU pipeline with SEQUENTIAL l2r 25-elem sums.
//
// Perf history:
//  R5/R8 ~56-59us hist: 25 atomics x 4096 blocks on 2 cache lines -> fixed
//    by replica arrays (R9). R6 210us: per-block __threadfence storm.
//  R9(block-staged) / R10(divergent) / R11(wave-staged) all ~28.5 total,
//    hist ~22us: load pattern and intra-block sync are NOT the limiter.
//  R12: structural overhead attack. (a) finalize fused into hist via
//    last-block protocol: bin atomics are device-coherent (TCC); ordering
//    needs only wave-local s_waitcnt vmcnt(0) before the done-increment --
//    NO threadfence (that was R6's storm). Counter+replicas re-zeroed by
//    the single leading memset each launch => deterministic. (b) NREP
//    64->128 halves per-line L2 RMW serialization at block end.
//
// ws layout: 128 replicas x 64 dwords (bins 0..24) = 32 KB; done counter
// at dword [128*64]; memset covers all of it.

#define KCLS 5
#define NREP 128

// XLA CPU full-reduce: init 0.0f, sequential left-to-right adds.
__device__ __forceinline__ float seq25(const float* a) {
    float res = 0.0f;
#pragma unroll
    for (int i = 0; i < 25; ++i) res = __fadd_rn(res, a[i]);
    return res;
}

__device__ void kappa_finalize_device(const unsigned int* cnt,
                                      float* out, int n) {
    const float fn = (float)n;  // 2^22, exact
    float conf[25];
#pragma unroll
    for (int k = 0; k < 25; ++k)
        conf[k] = __fdiv_rn((float)cnt[k], fn);  // exact

    float w[25];
#pragma unroll
    for (int i = 0; i < KCLS; ++i)
#pragma unroll
        for (int j = 0; j < KCLS; ++j)
            w[i * KCLS + j] = (float)((i - j) * (i - j)) / 16.0f;  // exact

    float mt[KCLS], mp[KCLS];
#pragma unroll
    for (int i = 0; i < KCLS; ++i) {
        float s = 0.0f;
#pragma unroll
        for (int j = 0; j < KCLS; ++j) s = __fadd_rn(s, conf[i * KCLS + j]);
        mt[i] = s;  // exact: multiples of 2^-22
    }
#pragma unroll
    for (int j = 0; j < KCLS; ++j) {
        float s = 0.0f;
#pragma unroll
        for (int i = 0; i < KCLS; ++i) s = __fadd_rn(s, conf[i * KCLS + j]);
        mp[j] = s;
    }

    float a[25], b[25];
#pragma unroll
    for (int k = 0; k < 25; ++k) {
        a[k] = __fmul_rn(conf[k], w[k]);                 // RN mul (no FMA)
        float e = __fmul_rn(mt[k / KCLS], mp[k % KCLS]); // outer, RN
        b[k] = __fmul_rn(e, w[k]);                       // RN mul
    }

    float num = seq25(a);
    float den = seq25(b);
    float den2 = __fadd_rn(den, 1e-7f);   // weak scalar -> f32
    float q = __fdiv_rn(num, den2);
    float kappa = __fsub_rn(1.0f, q);
    out[0] = -kappa;
}

__global__ __launch_bounds__(256, 8) void kappa_hist(const float* __restrict__ x,
                                                     const int* __restrict__ tgt,
                                                     unsigned int* __restrict__ gcnt,
                                                     float* __restrict__ out,
                                                     int n, int nblocks) {
    __shared__ unsigned int h[128];   // 4 waves x 32-slot histograms
    const int tid = threadIdx.x;
    const int lane = tid & 63;
    unsigned int* hw = h + ((tid >> 6) << 5);
    if (lane < 32) hw[lane] = 0u;     // wave-local init; per-wave LDS FIFO

    const int t = blockIdx.x * 256 + tid;   // 4 rows/thread
    const float4* xv = (const float4*)x;
    float f[20];
#pragma unroll
    for (int k = 0; k < 5; ++k) {
        float4 v = xv[t * 5 + k];     // 80B lane stride: proven non-limiting
        f[4 * k + 0] = v.x;
        f[4 * k + 1] = v.y;
        f[4 * k + 2] = v.z;
        f[4 * k + 3] = v.w;
    }
    const int4 tg = ((const int4*)tgt)[t];  // coalesced
    const int tgv[4] = {tg.x, tg.y, tg.z, tg.w};
#pragma unroll
    for (int r = 0; r < 4; ++r) {
        const float* fr = f + 5 * r;
        float m = fr[0];
        int k = 0;
#pragma unroll
        for (int j = 1; j < KCLS; ++j)
            if (fr[j] > m) { m = fr[j]; k = j; }   // first-max-wins
        atomicAdd(&hw[tgv[r] * KCLS + k], 1u);
    }
    __syncthreads();                  // merge waves (only barrier)

    // ---- wave 0 only from here on (other waves exit) ----
    if (tid >= 64) return;

    if (tid < KCLS * KCLS) {
        unsigned int s = h[tid] + h[32 + tid] + h[64 + tid] + h[96 + tid];
        // replica spread: 32 blocks share a replica; replicas 256B apart
        if (s) atomicAdd(&gcnt[(blockIdx.x & (NREP - 1)) * 64 + tid], s);
    }

    // last-block detection. The bin atomics above were issued by THIS wave;
    // vmcnt(0) guarantees they have performed at the coherence point (TCC)
    // before the done-increment is issued. No cache fence needed: every
    // cross-block access in this protocol is a device-coherent atomic.
    int last = 0;
    if (tid == 0) {
        asm volatile("s_waitcnt vmcnt(0)" ::: "memory");
        unsigned int old = atomicAdd(&gcnt[NREP * 64], 1u);
        last = (old == (unsigned int)(nblocks - 1)) ? 1 : 0;
    }
    last = __shfl(last, 0, 64);       // wave-0 broadcast
    if (!last) return;

    // last block: all other blocks' bin atomics have performed. Read back
    // with atomic loads (bypass L1), sum replicas per bin.
    if (tid < KCLS * KCLS) {
        unsigned int s = 0;
#pragma unroll 4
        for (int r = 0; r < NREP; ++r)
            s += atomicAdd(&gcnt[r * 64 + tid], 0u);   // atomic read
        h[tid] = s;                    // same-wave LDS handoff (lgkmcnt)
    }
    if (tid == 0)
        kappa_finalize_device(h, out, n);   // cold path; spills ok
}

extern "C" void kernel_launch(void* const* d_in, const int* in_sizes, int n_in,
                              void* d_out, int out_size, void* d_ws, size_t ws_size,
                              hipStream_t stream) {
    const float* x = (const float*)d_in[0];
    const int* tgt = (const int*)d_in[1];
    float* out = (float*)d_out;
    unsigned int* cnt = (unsigned int*)d_ws;

    const int n = in_sizes[1];          // rows (4194304 = 2^22)
    const int nblocks = n / 1024;       // 4096 blocks, 1024 rows each

    hipMemsetAsync(cnt, 0, (NREP * 64 + 64) * sizeof(unsigned int), stream);
    kappa_hist<<<nblocks, 256, 0, stream>>>(x, tgt, cnt, out, n, nblocks);
}

// Round 13
// 40.695 us; speedup vs baseline: 1.7514x; 1.7514x over previous
//
#include <hip/hip_runtime.h>

// QuadraticWeightedKappa: N=4194304 rows x 5 classes (f32 logits), int32
// targets. Output: one f32 scalar -kappa.
//
// Correctness model (locked in R5, absmax=0.0): counts = first-max-wins raw
// argmax; finalize = f32 XLA-CPU pipeline with SEQUENTIAL l2r 25-elem sums.
//
// Perf history:
//  R5/R8 ~56-59us: 25 atomics x 4096 blocks on 2 lines = L2 RMW floor.
//  R6 210us: per-block __threadfence => cross-XCD invalidate storm.
//  R9/R10/R11 ~28.5: replica atomics; hist ~22us; load pattern & intra-block
//    sync proven non-limiting (3 structures, same time).
//  R12 71us REGRESSION: fused finalize + __launch_bounds__(256,8) capped
//    VGPR at 64 with a ~110-reg cold path inline -> hot f[20] spilled to
//    scratch (VGPR 36->32, VALUBusy 4.1->2.5). Lesson: no min-occupancy
//    bound on kernels with fat cold paths.
//  R13: per-block STORE slots instead of atomics. Block b fully overwrites
//    ws[b][0..31] every launch => no memset (poison-safe), no atomics, no
//    done counter. Small finalize dispatch reduces [4096][32] with
//    coalesced uint4 loads. 2 dispatches total. Hist body == R10 (proven).
//
// ws layout: [nblocks][32] uint = 512 KB @ nblocks=4096.

#define KCLS 5

__global__ __launch_bounds__(256) void kappa_hist(const float* __restrict__ x,
                                                  const int* __restrict__ tgt,
                                                  unsigned int* __restrict__ ws) {
    __shared__ unsigned int h[128];   // 4 waves x 32-slot histograms
    const int tid = threadIdx.x;
    const int lane = tid & 63;
    unsigned int* hw = h + ((tid >> 6) << 5);
    if (lane < 32) hw[lane] = 0u;     // wave-local init; per-wave LDS FIFO

    const int t = blockIdx.x * 256 + tid;   // 4 rows/thread
    const float4* xv = (const float4*)x;
    float f[20];
#pragma unroll
    for (int k = 0; k < 5; ++k) {
        float4 v = xv[t * 5 + k];     // 80B lane stride: proven non-limiting
        f[4 * k + 0] = v.x;
        f[4 * k + 1] = v.y;
        f[4 * k + 2] = v.z;
        f[4 * k + 3] = v.w;
    }
    const int4 tg = ((const int4*)tgt)[t];  // coalesced
    const int tgv[4] = {tg.x, tg.y, tg.z, tg.w};
#pragma unroll
    for (int r = 0; r < 4; ++r) {
        const float* fr = f + 5 * r;
        float m = fr[0];
        int k = 0;
#pragma unroll
        for (int j = 1; j < KCLS; ++j)
            if (fr[j] > m) { m = fr[j]; k = j; }   // first-max-wins
        atomicAdd(&hw[tgv[r] * KCLS + k], 1u);
    }
    __syncthreads();                  // merge waves (only barrier)

    // per-block result slot: plain coalesced stores, fully overwritten
    // every launch (slots 25..31 = 0) -> no memset, no atomics anywhere.
    if (tid < 32) {
        unsigned int s = 0;
        if (tid < KCLS * KCLS)
            s = h[tid] + h[32 + tid] + h[64 + tid] + h[96 + tid];
        ws[blockIdx.x * 32 + tid] = s;
    }
}

// XLA CPU full-reduce: init 0.0f, sequential left-to-right adds.
__device__ __forceinline__ float seq25(const float* a) {
    float res = 0.0f;
#pragma unroll
    for (int i = 0; i < 25; ++i) res = __fadd_rn(res, a[i]);
    return res;
}

__global__ __launch_bounds__(256) void kappa_finalize(const unsigned int* __restrict__ ws,
                                                      float* __restrict__ out,
                                                      int n, int nblocks) {
    __shared__ unsigned int lp[256][4];   // per-thread uint4 partials
    __shared__ unsigned int cnt[25];
    const int tid = threadIdx.x;

    // thread t: column-chunk c = t&7 (bins 4c..4c+3), rows t>>3 + 32k.
    // flat uint4 index r*8+c: at k=0 indices are exactly 0..255 -> coalesced.
    const uint4* w4 = (const uint4*)ws;
    const int c = tid & 7, r0 = tid >> 3;
    uint4 acc = make_uint4(0u, 0u, 0u, 0u);
    for (int r = r0; r < nblocks; r += 32) {
        uint4 v = w4[r * 8 + c];
        acc.x += v.x; acc.y += v.y; acc.z += v.z; acc.w += v.w;
    }
    lp[tid][0] = acc.x; lp[tid][1] = acc.y; lp[tid][2] = acc.z; lp[tid][3] = acc.w;
    __syncthreads();

    if (tid < KCLS * KCLS) {
        const int cc = tid >> 2, comp = tid & 3;   // chunk, component
        unsigned int s = 0;
#pragma unroll
        for (int g = 0; g < 32; ++g) s += lp[g * 8 + cc][comp];
        cnt[tid] = s;
    }
    __syncthreads();
    if (tid != 0) return;

    // ---- locked bit-exact f32 pipeline (XLA-CPU semantics) ----
    const float fn = (float)n;  // 2^22, exact
    float conf[25];
#pragma unroll
    for (int k = 0; k < 25; ++k)
        conf[k] = __fdiv_rn((float)cnt[k], fn);  // exact

    float w[25];
#pragma unroll
    for (int i = 0; i < KCLS; ++i)
#pragma unroll
        for (int j = 0; j < KCLS; ++j)
            w[i * KCLS + j] = (float)((i - j) * (i - j)) / 16.0f;  // exact

    float mt[KCLS], mp[KCLS];
#pragma unroll
    for (int i = 0; i < KCLS; ++i) {
        float s = 0.0f;
#pragma unroll
        for (int j = 0; j < KCLS; ++j) s = __fadd_rn(s, conf[i * KCLS + j]);
        mt[i] = s;  // exact: multiples of 2^-22
    }
#pragma unroll
    for (int j = 0; j < KCLS; ++j) {
        float s = 0.0f;
#pragma unroll
        for (int i = 0; i < KCLS; ++i) s = __fadd_rn(s, conf[i * KCLS + j]);
        mp[j] = s;
    }

    float a[25], b[25];
#pragma unroll
    for (int k = 0; k < 25; ++k) {
        a[k] = __fmul_rn(conf[k], w[k]);                 // RN mul (no FMA)
        float e = __fmul_rn(mt[k / KCLS], mp[k % KCLS]); // outer, RN
        b[k] = __fmul_rn(e, w[k]);                       // RN mul
    }

    float num = seq25(a);
    float den = seq25(b);
    float den2 = __fadd_rn(den, 1e-7f);   // weak scalar -> f32
    float q = __fdiv_rn(num, den2);
    float kappa = __fsub_rn(1.0f, q);
    out[0] = -kappa;
}

extern "C" void kernel_launch(void* const* d_in, const int* in_sizes, int n_in,
                              void* d_out, int out_size, void* d_ws, size_t ws_size,
                              hipStream_t stream) {
    const float* x = (const float*)d_in[0];
    const int* tgt = (const int*)d_in[1];
    float* out = (float*)d_out;
    unsigned int* ws = (unsigned int*)d_ws;

    const int n = in_sizes[1];          // rows (4194304 = 2^22)
    const int nblocks = n / 1024;       // 4096 blocks, 1024 rows each

    kappa_hist<<<nblocks, 256, 0, stream>>>(x, tgt, ws);
    kappa_finalize<<<1, 256, 0, stream>>>(ws, out, n, nblocks);
}

// Round 14
// 23.023 us; speedup vs baseline: 3.0958x; 1.7676x over previous
//
#include <hip/hip_runtime.h>

// QuadraticWeightedKappa: N=4194304 rows x 5 classes (f32 logits), int32
// targets. Output: one f32 scalar -kappa.
//
// Correctness model (locked in R5, absmax=0.0): counts = first-max-wins raw
// argmax; finalize = f32 XLA-CPU pipeline with SEQUENTIAL l2r 25-elem sums.
//
// Perf history:
//  R5/R8 ~56-59us: 25 atomics x 4096 blocks on 2 lines = L2 RMW serial floor.
//  R6 210us: per-block __threadfence => cross-XCD invalidate storm.
//  R9/R10/R11 ~28.5 total: replica atomics fixed the floor; hist ~22us;
//    global-load pattern & intra-block sync proven non-limiting.
//  R12 71us: fused finalize + launch_bounds(256,8) -> hot-path scratch spill.
//  R13 40.7us: per-block stores (good) but single-block finalize read 512KB
//    -> ~15us latency-bound reduce. Lesson: slot tables must stay small.
//  R14: 512 blocks x 8 grid-stride tiles (R10 body per tile, no in-loop
//    barriers; LDS histograms accumulate across tiles; ONE merge/block).
//    Slot table 64KB; finalize reads 4 uint4/thread. 2 dispatches, no
//    memset, no atomics, deterministic.
//
// ws layout: [512][32] uint = 64 KB, fully overwritten every launch.

#define KCLS 5
#define HBLK 512          // hist blocks
#define TILES 8           // grid-stride tiles per block

__global__ __launch_bounds__(256) void kappa_hist(const float* __restrict__ x,
                                                  const int* __restrict__ tgt,
                                                  unsigned int* __restrict__ ws) {
    __shared__ unsigned int h[128];   // 4 waves x 32-slot histograms
    const int tid = threadIdx.x;
    const int lane = tid & 63;
    unsigned int* hw = h + ((tid >> 6) << 5);
    if (lane < 32) hw[lane] = 0u;     // wave-local init; per-wave LDS FIFO
                                      // (only this wave touches hw before
                                      // the single end-of-kernel barrier)

    const float4* xv = (const float4*)x;
#pragma unroll 1
    for (int s = 0; s < TILES; ++s) {
        const int t = (s * HBLK + blockIdx.x) * 256 + tid;   // 4 rows/thread
        float f[20];
#pragma unroll
        for (int k = 0; k < 5; ++k) {
            float4 v = xv[t * 5 + k]; // 80B lane stride: proven non-limiting
            f[4 * k + 0] = v.x;
            f[4 * k + 1] = v.y;
            f[4 * k + 2] = v.z;
            f[4 * k + 3] = v.w;
        }
        const int4 tg = ((const int4*)tgt)[t];  // coalesced
        const int tgv[4] = {tg.x, tg.y, tg.z, tg.w};
#pragma unroll
        for (int r = 0; r < 4; ++r) {
            const float* fr = f + 5 * r;
            float m = fr[0];
            int k = 0;
#pragma unroll
            for (int j = 1; j < KCLS; ++j)
                if (fr[j] > m) { m = fr[j]; k = j; }   // first-max-wins
            atomicAdd(&hw[tgv[r] * KCLS + k], 1u);
        }
    }
    __syncthreads();                  // merge waves (the only barrier)

    // per-block result slot: plain coalesced stores, fully overwritten
    // every launch (slots 25..31 = 0) -> no memset, no atomics anywhere.
    if (tid < 32) {
        unsigned int s = 0;
        if (tid < KCLS * KCLS)
            s = h[tid] + h[32 + tid] + h[64 + tid] + h[96 + tid];
        ws[blockIdx.x * 32 + tid] = s;
    }
}

// XLA CPU full-reduce: init 0.0f, sequential left-to-right adds.
__device__ __forceinline__ float seq25(const float* a) {
    float res = 0.0f;
#pragma unroll
    for (int i = 0; i < 25; ++i) res = __fadd_rn(res, a[i]);
    return res;
}

__global__ __launch_bounds__(256) void kappa_finalize(const unsigned int* __restrict__ ws,
                                                      float* __restrict__ out,
                                                      int n) {
    __shared__ unsigned int lp[256][4];   // per-thread uint4 partials
    __shared__ unsigned int cnt[25];
    const int tid = threadIdx.x;

    // [512][32] uint = 4096 uint4. thread t: chunk c=t&7 (bins 4c..4c+3),
    // rows r = t>>3 + 32k, k=0..15. k=0 covers flat idx 0..255: coalesced.
    const uint4* w4 = (const uint4*)ws;
    const int c = tid & 7, r0 = tid >> 3;
    uint4 acc = make_uint4(0u, 0u, 0u, 0u);
#pragma unroll
    for (int k = 0; k < HBLK / 32; ++k) {
        uint4 v = w4[(r0 + 32 * k) * 8 + c];
        acc.x += v.x; acc.y += v.y; acc.z += v.z; acc.w += v.w;
    }
    lp[tid][0] = acc.x; lp[tid][1] = acc.y; lp[tid][2] = acc.z; lp[tid][3] = acc.w;
    __syncthreads();

    if (tid < KCLS * KCLS) {
        const int cc = tid >> 2, comp = tid & 3;   // chunk, component
        unsigned int s = 0;
#pragma unroll
        for (int g = 0; g < 32; ++g) s += lp[g * 8 + cc][comp];
        cnt[tid] = s;
    }
    __syncthreads();
    if (tid != 0) return;

    // ---- locked bit-exact f32 pipeline (XLA-CPU semantics) ----
    const float fn = (float)n;  // 2^22, exact
    float conf[25];
#pragma unroll
    for (int k = 0; k < 25; ++k)
        conf[k] = __fdiv_rn((float)cnt[k], fn);  // exact

    float w[25];
#pragma unroll
    for (int i = 0; i < KCLS; ++i)
#pragma unroll
        for (int j = 0; j < KCLS; ++j)
            w[i * KCLS + j] = (float)((i - j) * (i - j)) / 16.0f;  // exact

    float mt[KCLS], mp[KCLS];
#pragma unroll
    for (int i = 0; i < KCLS; ++i) {
        float s = 0.0f;
#pragma unroll
        for (int j = 0; j < KCLS; ++j) s = __fadd_rn(s, conf[i * KCLS + j]);
        mt[i] = s;  // exact: multiples of 2^-22
    }
#pragma unroll
    for (int j = 0; j < KCLS; ++j) {
        float s = 0.0f;
#pragma unroll
        for (int i = 0; i < KCLS; ++i) s = __fadd_rn(s, conf[i * KCLS + j]);
        mp[j] = s;
    }

    float a[25], b[25];
#pragma unroll
    for (int k = 0; k < 25; ++k) {
        a[k] = __fmul_rn(conf[k], w[k]);                 // RN mul (no FMA)
        float e = __fmul_rn(mt[k / KCLS], mp[k % KCLS]); // outer, RN
        b[k] = __fmul_rn(e, w[k]);                       // RN mul
    }

    float num = seq25(a);
    float den = seq25(b);
    float den2 = __fadd_rn(den, 1e-7f);   // weak scalar -> f32
    float q = __fdiv_rn(num, den2);
    float kappa = __fsub_rn(1.0f, q);
    out[0] = -kappa;
}

extern "C" void kernel_launch(void* const* d_in, const int* in_sizes, int n_in,
                              void* d_out, int out_size, void* d_ws, size_t ws_size,
                              hipStream_t stream) {
    const float* x = (const float*)d_in[0];
    const int* tgt = (const int*)d_in[1];
    float* out = (float*)d_out;
    unsigned int* ws = (unsigned int*)d_ws;

    const int n = in_sizes[1];          // rows (4194304 = 2^22)
    // HBLK * TILES * 1024 rows == n (512 * 8 * 1024 = 2^22), exact

    kappa_hist<<<HBLK, 256, 0, stream>>>(x, tgt, ws);
    kappa_finalize<<<1, 256, 0, stream>>>(ws, out, n);
}